// Round 6
// baseline (108.681 us; speedup 1.0000x reference)
//
#include <hip/hip_runtime.h>
#include <stdint.h>

// Shapes fixed by setup_inputs: B=4, D=20, H=W=128, HW=16384, K=65536 voxels.
// Block = 64 voxels x 4 waves. Stage the whole block tile (pred 60ch, gt 60ch,
// cmask 20ch; [channel][voxel] f32) into LDS via async global_load_lds width=16
// (35 instrs, fire-and-forget -> full MLP, no VGPR destinations). Wave
// w=(ri<<1)|cj computes the 10x10 (rows i=ri*10.., cols j=cj*10..) sub-matrix
// from LDS; partial row-mins/col-mins are combined by reusing the tile LDS.
#define HW  16384
#define VPB 64

// smem float offsets (phase A: staging tile; phase B reuses pred+gt region)
#define OFF_PRED 0      // 60*64 floats
#define OFF_GT   3840   // 60*64
#define OFF_CM   7680   // 20*64  (kept intact through finalize)
#define OFF_RMM  0      // 20 rows x 2 cj x 64   (reuses pred)
#define OFF_RMA  2560   // 20 x 2 x 64           (reuses pred tail + gt head)
#define OFF_D2S  5120   // 20 cols x 2 ri x 64   (reuses gt tail)
#define OFF_MX   8960   // 4 waves x 64
#define SMEM_F   9216   // 36864 bytes -> 4 blocks/CU

__device__ __forceinline__ void gload_lds16(const float* g, float* l) {
    __builtin_amdgcn_global_load_lds(
        (const __attribute__((address_space(1))) uint32_t*)g,
        (__attribute__((address_space(3))) uint32_t*)l, 16, 0, 0);
}

__global__ __launch_bounds__(256, 4) void chamfer_main(
    const float* __restrict__ pred,   // [B, 60, HW]  channel c*20+i
    const float* __restrict__ gt,     // [B, 60, HW]  channel j*3+c
    const float* __restrict__ cmask,  // [B, 20, HW]
    const float* __restrict__ vmask,  // [B, HW]
    const float* __restrict__ pnum,   // [B, HW]
    const float* __restrict__ gnum,   // [B, HW]
    float* __restrict__ ws)
{
    __shared__ float smem[SMEM_F];
    const int lane = threadIdx.x & 63;   // voxel within block
    const int w    = threadIdx.x >> 6;   // wave 0..3
    const int ri   = w >> 1;             // row group (10 src rows)
    const int cj   = w & 1;              // col group (10 dst cols)
    const int k    = blockIdx.x * VPB + lane;
    const int b    = k >> 14;
    const int hw0  = (blockIdx.x * VPB) & (HW - 1);
    const float* gb = pred  + (size_t)b * 60 * HW + hw0;
    const float* tb = gt    + (size_t)b * 60 * HW + hw0;
    const float* cb = cmask + (size_t)b * 20 * HW + hw0;

    // ---- async stage: 35 x width-16 (lane sub-channel = lane>>4, 4 voxels/lane)
    {
        const int sub = lane >> 4;          // which of 4 channels in this instr
        const int vo  = (lane & 15) * 4;    // voxel offset (4 consecutive voxels)
        for (int t = w; t < 35; t += 4) {   // wave w issues instrs t%4==w
            const float* src; int ch0, region;
            if (t < 15)      { src = gb; ch0 = t * 4;        region = OFF_PRED; }
            else if (t < 30) { src = tb; ch0 = (t - 15) * 4; region = OFF_GT;   }
            else             { src = cb; ch0 = (t - 30) * 4; region = OFF_CM;   }
            gload_lds16(src + (size_t)(ch0 + sub) * HW + vo,
                        &smem[region + ch0 * 64]);
        }
    }
    // wave 0 prefetches its finalize scalars while staging is in flight
    float vw = 0.f, pn = 0.f, gn = 0.f;
    if (w == 0) { vw = vmask[k]; pn = pnum[k]; gn = gnum[k]; }
    asm volatile("s_waitcnt vmcnt(0)" ::: "memory");  // drain async LDS-stores
    __syncthreads();

    // ---- compute 10x10 sub-matrix from LDS
    const int j0 = cj * 10, i0 = ri * 10;
    float dx[10], dy[10], dz[10];
    #pragma unroll
    for (int jj = 0; jj < 10; ++jj) {
        dx[jj] = smem[OFF_GT + (3 * (j0 + jj)    ) * 64 + lane];
        dy[jj] = smem[OFF_GT + (3 * (j0 + jj) + 1) * 64 + lane];
        dz[jj] = smem[OFF_GT + (3 * (j0 + jj) + 2) * 64 + lane];
    }
    unsigned mybits = 0u;                 // local bit jj
    #pragma unroll
    for (int jj = 0; jj < 10; ++jj)
        if (smem[OFF_CM + (j0 + jj) * 64 + lane] > 0.f) mybits |= 1u << jj;

    const float INF = __int_as_float(0x7f800000);
    float d2s[10], rmm[10], rma[10], locmax = 0.f;
    #pragma unroll
    for (int t = 0; t < 10; ++t) { d2s[t] = INF; rmm[t] = INF; rma[t] = INF; }

    #pragma unroll
    for (int r = 0; r < 10; ++r) {
        const int i = i0 + r;
        const float sx = smem[OFF_PRED + (i)      * 64 + lane];
        const float sy = smem[OFF_PRED + (20 + i) * 64 + lane];
        const float sz = smem[OFF_PRED + (40 + i) * 64 + lane];
        #pragma unroll
        for (int jj = 0; jj < 10; ++jj) {
            float d = fabsf(sx - dx[jj]) + fabsf(sy - dy[jj]) + fabsf(sz - dz[jj]);
            locmax  = fmaxf(locmax, d);
            d2s[jj] = fminf(d2s[jj], d);
            rma[r]  = fminf(rma[r], d);
            rmm[r]  = fminf(rmm[r], ((mybits >> jj) & 1u) ? d : INF);
        }
    }
    __syncthreads();   // everyone done READING pred/gt before overwrite

    #pragma unroll
    for (int r = 0; r < 10; ++r) {
        smem[OFF_RMM + ((i0 + r) * 2 + cj) * 64 + lane] = rmm[r];
        smem[OFF_RMA + ((i0 + r) * 2 + cj) * 64 + lane] = rma[r];
        smem[OFF_D2S + ((j0 + r) * 2 + ri) * 64 + lane] = d2s[r];
    }
    smem[OFF_MX + w * 64 + lane] = locmax;
    __syncthreads();

    // ---- finalize: wave 0, lane = voxel
    if (w == 0) {
        unsigned cmbits = 0u;
        #pragma unroll
        for (int j = 0; j < 20; ++j)
            if (smem[OFF_CM + j * 64 + lane] > 0.f) cmbits |= 1u << j;
        // if any masked col: s2d_i = masked row-min; else all-min (+maxd later)
        const int selbase = cmbits ? OFF_RMM : OFF_RMA;
        float srcA = 0.f;
        #pragma unroll
        for (int i = 0; i < 20; ++i)
            srcA += fminf(smem[selbase + (i * 2)     * 64 + lane],
                          smem[selbase + (i * 2 + 1) * 64 + lane]);
        float dsum = 0.f;
        #pragma unroll
        for (int j = 0; j < 20; ++j) {
            float m = fminf(smem[OFF_D2S + (j * 2)     * 64 + lane],
                            smem[OFF_D2S + (j * 2 + 1) * 64 + lane]);
            if ((cmbits >> j) & 1u) dsum += m;
        }
        float mx = fmaxf(fmaxf(smem[OFF_MX + lane],       smem[OFF_MX + 64 + lane]),
                         fmaxf(smem[OFF_MX + 128 + lane], smem[OFF_MX + 192 + lane]));

        float vals[7];
        vals[0] = srcA * vw;                          // src-loss min-sum
        vals[1] = (cmbits == 0u) ? 20.f * vw : 0.f;   // rows needing +max_d
        vals[2] = dsum * vw;                          // dst-loss numerator
        vals[3] = vw * (float)__popc(cmbits);         // dst-loss denominator
        const float diff = pn - gn;
        const float ad = fabsf(diff);
        vals[4] = ((ad < 1.f) ? 0.5f * diff * diff : (ad - 0.5f)) * vw;
        vals[5] = vw;                                 // wsum
        vals[6] = (vw > 0.f) ? mx : 0.f;              // masked max

        #pragma unroll
        for (int o = 32; o > 0; o >>= 1) {
            #pragma unroll
            for (int x = 0; x < 6; ++x) vals[x] += __shfl_down(vals[x], o);
            vals[6] = fmaxf(vals[6], __shfl_down(vals[6], o));
        }
        if (lane == 0) {
            #pragma unroll
            for (int x = 0; x < 6; ++x) atomicAdd(&ws[x], vals[x]);
            atomicMax((int*)&ws[6], __float_as_int(vals[6]));  // dist>=0: int max == float max
        }
    }
}

__global__ void chamfer_fin(const float* __restrict__ ws, float* __restrict__ out)
{
    const float maxd   = ws[6];
    const float wsum   = ws[5];
    const float loss_s = (ws[0] + ws[1] * maxd) / (wsum * 20.f);
    const float loss_d = ws[2] / ws[3];
    const float numl   = ws[4] / ws[5];
    out[0] = loss_s + loss_d + 0.1f * numl;
}

extern "C" void kernel_launch(void* const* d_in, const int* in_sizes, int n_in,
                              void* d_out, int out_size, void* d_ws, size_t ws_size,
                              hipStream_t stream)
{
    const float* pred  = (const float*)d_in[0];
    const float* gt    = (const float*)d_in[1];
    const float* cmask = (const float*)d_in[2];
    const float* vmask = (const float*)d_in[3];
    const float* pnum  = (const float*)d_in[4];
    const float* gnum  = (const float*)d_in[5];
    float* out = (float*)d_out;
    float* ws  = (float*)d_ws;

    const int nvox = in_sizes[3];            // B*H*W = 65536
    hipMemsetAsync(ws, 0, 8 * sizeof(float), stream);
    chamfer_main<<<nvox / VPB, 256, 0, stream>>>(pred, gt, cmask, vmask, pnum, gnum, ws);
    chamfer_fin<<<1, 1, 0, stream>>>(ws, out);
}

// Round 7
// 22.062 us; speedup vs baseline: 4.9263x; 4.9263x over previous
//
#include <hip/hip_runtime.h>
#include <stdint.h>

// Shapes fixed by setup_inputs: B=4, D=20, H=W=128, HW=16384, K=65536 voxels.
// Block = 64 voxels x 4 waves. Stage the block tile (pred 60ch, gt 60ch,
// cmask 20ch; [channel][voxel] f32) into LDS via async global_load_lds w=16.
// Wave w=(ri<<1)|cj computes the 10x10 sub-matrix from LDS; partials combined
// by reusing tile LDS. NO global atomics: each block stores its 7 partials to
// a private ws record; a 1-wave finalize kernel reduces the 1024 records.
// (R2-R6 lesson: 7168 same-line atomics serialized ~90us of tail.)
#define HW   16384
#define VPB  64
#define NBLK 1024

// smem float offsets (phase A: staging tile; phase B reuses pred+gt region)
#define OFF_PRED 0      // 60*64 floats
#define OFF_GT   3840   // 60*64
#define OFF_CM   7680   // 20*64  (kept intact through finalize)
#define OFF_RMM  0      // 20 rows x 2 cj x 64   (reuses pred)
#define OFF_RMA  2560   // 20 x 2 x 64           (reuses pred tail + gt head)
#define OFF_D2S  5120   // 20 cols x 2 ri x 64   (reuses gt tail)
#define OFF_MX   8960   // 4 waves x 64
#define SMEM_F   9216   // 36864 bytes -> 4 blocks/CU

__device__ __forceinline__ void gload_lds16(const float* g, float* l) {
    __builtin_amdgcn_global_load_lds(
        (const __attribute__((address_space(1))) uint32_t*)g,
        (__attribute__((address_space(3))) uint32_t*)l, 16, 0, 0);
}

__global__ __launch_bounds__(256, 4) void chamfer_main(
    const float* __restrict__ pred,   // [B, 60, HW]  channel c*20+i
    const float* __restrict__ gt,     // [B, 60, HW]  channel j*3+c
    const float* __restrict__ cmask,  // [B, 20, HW]
    const float* __restrict__ vmask,  // [B, HW]
    const float* __restrict__ pnum,   // [B, HW]
    const float* __restrict__ gnum,   // [B, HW]
    float* __restrict__ ws)
{
    __shared__ float smem[SMEM_F];
    const int lane = threadIdx.x & 63;   // voxel within block
    const int w    = threadIdx.x >> 6;   // wave 0..3
    const int ri   = w >> 1;             // row group (10 src rows)
    const int cj   = w & 1;              // col group (10 dst cols)
    const int k    = blockIdx.x * VPB + lane;
    const int b    = k >> 14;
    const int hw0  = (blockIdx.x * VPB) & (HW - 1);
    const float* gb = pred  + (size_t)b * 60 * HW + hw0;
    const float* tb = gt    + (size_t)b * 60 * HW + hw0;
    const float* cb = cmask + (size_t)b * 20 * HW + hw0;

    // ---- async stage: 35 x width-16 (lane sub-channel = lane>>4, 4 voxels/lane)
    {
        const int sub = lane >> 4;          // which of 4 channels in this instr
        const int vo  = (lane & 15) * 4;    // voxel offset (4 consecutive voxels)
        for (int t = w; t < 35; t += 4) {   // wave w issues instrs t%4==w
            const float* src; int ch0, region;
            if (t < 15)      { src = gb; ch0 = t * 4;        region = OFF_PRED; }
            else if (t < 30) { src = tb; ch0 = (t - 15) * 4; region = OFF_GT;   }
            else             { src = cb; ch0 = (t - 30) * 4; region = OFF_CM;   }
            gload_lds16(src + (size_t)(ch0 + sub) * HW + vo,
                        &smem[region + ch0 * 64]);
        }
    }
    // wave 0 prefetches its finalize scalars while staging is in flight
    float vw = 0.f, pn = 0.f, gn = 0.f;
    if (w == 0) { vw = vmask[k]; pn = pnum[k]; gn = gnum[k]; }
    asm volatile("s_waitcnt vmcnt(0)" ::: "memory");  // drain async LDS-stores
    __syncthreads();

    // ---- compute 10x10 sub-matrix from LDS
    const int j0 = cj * 10, i0 = ri * 10;
    float dx[10], dy[10], dz[10];
    #pragma unroll
    for (int jj = 0; jj < 10; ++jj) {
        dx[jj] = smem[OFF_GT + (3 * (j0 + jj)    ) * 64 + lane];
        dy[jj] = smem[OFF_GT + (3 * (j0 + jj) + 1) * 64 + lane];
        dz[jj] = smem[OFF_GT + (3 * (j0 + jj) + 2) * 64 + lane];
    }
    unsigned mybits = 0u;                 // local bit jj
    #pragma unroll
    for (int jj = 0; jj < 10; ++jj)
        if (smem[OFF_CM + (j0 + jj) * 64 + lane] > 0.f) mybits |= 1u << jj;

    const float INF = __int_as_float(0x7f800000);
    float d2s[10], rmm[10], rma[10], locmax = 0.f;
    #pragma unroll
    for (int t = 0; t < 10; ++t) { d2s[t] = INF; rmm[t] = INF; rma[t] = INF; }

    #pragma unroll
    for (int r = 0; r < 10; ++r) {
        const int i = i0 + r;
        const float sx = smem[OFF_PRED + (i)      * 64 + lane];
        const float sy = smem[OFF_PRED + (20 + i) * 64 + lane];
        const float sz = smem[OFF_PRED + (40 + i) * 64 + lane];
        #pragma unroll
        for (int jj = 0; jj < 10; ++jj) {
            float d = fabsf(sx - dx[jj]) + fabsf(sy - dy[jj]) + fabsf(sz - dz[jj]);
            locmax  = fmaxf(locmax, d);
            d2s[jj] = fminf(d2s[jj], d);
            rma[r]  = fminf(rma[r], d);
            rmm[r]  = fminf(rmm[r], ((mybits >> jj) & 1u) ? d : INF);
        }
    }
    __syncthreads();   // everyone done READING pred/gt before overwrite

    #pragma unroll
    for (int r = 0; r < 10; ++r) {
        smem[OFF_RMM + ((i0 + r) * 2 + cj) * 64 + lane] = rmm[r];
        smem[OFF_RMA + ((i0 + r) * 2 + cj) * 64 + lane] = rma[r];
        smem[OFF_D2S + ((j0 + r) * 2 + ri) * 64 + lane] = d2s[r];
    }
    smem[OFF_MX + w * 64 + lane] = locmax;
    __syncthreads();

    // ---- finalize: wave 0, lane = voxel
    if (w == 0) {
        unsigned cmbits = 0u;
        #pragma unroll
        for (int j = 0; j < 20; ++j)
            if (smem[OFF_CM + j * 64 + lane] > 0.f) cmbits |= 1u << j;
        // if any masked col: s2d_i = masked row-min; else all-min (+maxd later)
        const int selbase = cmbits ? OFF_RMM : OFF_RMA;
        float srcA = 0.f;
        #pragma unroll
        for (int i = 0; i < 20; ++i)
            srcA += fminf(smem[selbase + (i * 2)     * 64 + lane],
                          smem[selbase + (i * 2 + 1) * 64 + lane]);
        float dsum = 0.f;
        #pragma unroll
        for (int j = 0; j < 20; ++j) {
            float m = fminf(smem[OFF_D2S + (j * 2)     * 64 + lane],
                            smem[OFF_D2S + (j * 2 + 1) * 64 + lane]);
            if ((cmbits >> j) & 1u) dsum += m;
        }
        float mx = fmaxf(fmaxf(smem[OFF_MX + lane],       smem[OFF_MX + 64 + lane]),
                         fmaxf(smem[OFF_MX + 128 + lane], smem[OFF_MX + 192 + lane]));

        float vals[7];
        vals[0] = srcA * vw;                          // src-loss min-sum
        vals[1] = (cmbits == 0u) ? 20.f * vw : 0.f;   // rows needing +max_d
        vals[2] = dsum * vw;                          // dst-loss numerator
        vals[3] = vw * (float)__popc(cmbits);         // dst-loss denominator
        const float diff = pn - gn;
        const float ad = fabsf(diff);
        vals[4] = ((ad < 1.f) ? 0.5f * diff * diff : (ad - 0.5f)) * vw;
        vals[5] = vw;                                 // wsum
        vals[6] = (vw > 0.f) ? mx : 0.f;              // masked max

        #pragma unroll
        for (int o = 32; o > 0; o >>= 1) {
            #pragma unroll
            for (int x = 0; x < 6; ++x) vals[x] += __shfl_down(vals[x], o);
            vals[6] = fmaxf(vals[6], __shfl_down(vals[6], o));
        }
        // NO atomics: private record per block (plain stores; kernel-boundary
        // coherence makes them visible to chamfer_fin on the same stream)
        if (lane == 0) {
            float* rec = ws + (size_t)blockIdx.x * 8;
            #pragma unroll
            for (int x = 0; x < 7; ++x) rec[x] = vals[x];
        }
    }
}

__global__ __launch_bounds__(64) void chamfer_fin(
    const float* __restrict__ ws, float* __restrict__ out)
{
    const int t = threadIdx.x;   // one wave: 64 lanes x 16 records
    float a[6] = {0.f, 0.f, 0.f, 0.f, 0.f, 0.f};
    float mx = 0.f;
    for (int r = t; r < NBLK; r += 64) {
        const float* rec = ws + (size_t)r * 8;
        #pragma unroll
        for (int v = 0; v < 6; ++v) a[v] += rec[v];
        mx = fmaxf(mx, rec[6]);
    }
    #pragma unroll
    for (int o = 32; o > 0; o >>= 1) {
        #pragma unroll
        for (int v = 0; v < 6; ++v) a[v] += __shfl_down(a[v], o);
        mx = fmaxf(mx, __shfl_down(mx, o));
    }
    if (t == 0) {
        const float loss_s = (a[0] + a[1] * mx) / (a[5] * 20.f);
        const float loss_d = a[2] / a[3];
        const float numl   = a[4] / a[5];
        out[0] = loss_s + loss_d + 0.1f * numl;
    }
}

extern "C" void kernel_launch(void* const* d_in, const int* in_sizes, int n_in,
                              void* d_out, int out_size, void* d_ws, size_t ws_size,
                              hipStream_t stream)
{
    const float* pred  = (const float*)d_in[0];
    const float* gt    = (const float*)d_in[1];
    const float* cmask = (const float*)d_in[2];
    const float* vmask = (const float*)d_in[3];
    const float* pnum  = (const float*)d_in[4];
    const float* gnum  = (const float*)d_in[5];
    float* out = (float*)d_out;
    float* ws  = (float*)d_ws;

    const int nvox = in_sizes[3];            // B*H*W = 65536
    chamfer_main<<<nvox / VPB, 256, 0, stream>>>(pred, gt, cmask, vmask, pnum, gnum, ws);
    chamfer_fin<<<1, 64, 0, stream>>>(ws, out);
}